// Round 6
// baseline (59.013 us; speedup 1.0000x reference)
//
#include <hip/hip_runtime.h>

#define B_ 8
#define Q_ 64
#define K_ 512
#define NU_ 512
#define D_ 512

typedef __attribute__((ext_vector_type(8))) _Float16 half8;
typedef __attribute__((ext_vector_type(4))) _Float16 half4;
typedef __attribute__((ext_vector_type(16))) float floatx16;

#define C2F 2.8853900817779268f  // 2*log2(e)

// ws float-layout
#define WS_V 0                      // v[0..511], vtot at [512]
#define WS_EQ 640                   // Eq: 8*64*512
#define WS_EK (640 + 262144)        // Ek: 8*512*512
#define WS_S (WS_EK + 2097152)      // S raw scores: 8*64*512
#define WS_FLOATS (WS_S + 262144)
#define AH_ELEMS 2359296            // 144 mt * 32 kc * 64 lanes * 8 (f16)
#define WH_ELEMS 262144             // 16 nt * 32 kc * 64 * 8 (f16)
#define WS_BYTES_MFMA (WS_FLOATS * 4 + (size_t)(AH_ELEMS + 2 * WH_ELEMS) * 2)

// ---------------------------------------------------------------------------
// Kernel 1: f32 -> f16 conversion into PRE-SWIZZLED MFMA fragment layout,
// + v-normalize (+ vtot at v[512]).
// Fragment layout: frag[((tile*32 + kc)*64 + lane)*8 + j] =
//   M[tile*32 + (lane&31)][kc*16 + (lane>>5)*8 + j]
// A-tiles: 144 (keys rows 0..4095, then query rows 4096..4607). W-tiles: 16.
// Wave-tasks: A 4608, Wk 512, Wq 512 -> blocks: 1152 + 128 + 128 + 1 (v).
// ---------------------------------------------------------------------------
__global__ __launch_bounds__(256) void convert_kernel(
    const float* __restrict__ query, const float* __restrict__ keys,
    const float* __restrict__ Wq, const float* __restrict__ Wk,
    const float* __restrict__ la, const float* __restrict__ scalar,
    _Float16* __restrict__ Afrag, _Float16* __restrict__ Wkfrag,
    _Float16* __restrict__ Wqfrag, float* __restrict__ v) {
  int bid = blockIdx.x;
  int t = threadIdx.x;
  if (bid == 1408) {  // v block
    __shared__ float red[4], red2[4];
    float x0 = la[t], x1 = la[t + 256];
    float ss = x0 * x0 + x1 * x1;
#pragma unroll
    for (int o = 1; o < 64; o <<= 1) ss += __shfl_xor(ss, o, 64);
    int wave = t >> 6, lane = t & 63;
    if (lane == 0) red[wave] = ss;
    __syncthreads();
    float tot = red[0] + red[1] + red[2] + red[3];
    float sc = rsqrtf(tot) * scalar[0];
    float v0 = x0 * sc, v1 = x1 * sc;
    v[t] = v0;
    v[t + 256] = v1;
    float sv = v0 + v1;
#pragma unroll
    for (int o = 1; o < 64; o <<= 1) sv += __shfl_xor(sv, o, 64);
    if (lane == 0) red2[wave] = sv;
    __syncthreads();
    if (t == 0) v[512] = red2[0] + red2[1] + red2[2] + red2[3];
    return;
  }
  int w = t >> 6, l = t & 63;
  int lr = l & 31, g = l >> 5;
  const float* src;
  _Float16* dst;
  int kc;
  if (bid < 1152) {  // A fragments
    int wid = bid * 4 + w;  // [0,4608)
    int mt = wid >> 5;
    kc = wid & 31;
    int row = mt * 32 + lr;
    src = (row < 4096) ? keys + (size_t)row * 512
                       : query + (size_t)(row - 4096) * 512;
    dst = Afrag + ((size_t)wid * 64 + l) * 8;
  } else if (bid < 1280) {  // Wk fragments
    int wid = (bid - 1152) * 4 + w;  // [0,512)
    int nt = wid >> 5;
    kc = wid & 31;
    src = Wk + (size_t)(nt * 32 + lr) * 512;
    dst = Wkfrag + ((size_t)wid * 64 + l) * 8;
  } else {  // Wq fragments
    int wid = (bid - 1280) * 4 + w;  // [0,512)
    int nt = wid >> 5;
    kc = wid & 31;
    src = Wq + (size_t)(nt * 32 + lr) * 512;
    dst = Wqfrag + ((size_t)wid * 64 + l) * 8;
  }
  int col = kc * 16 + g * 8;
  float4 x0 = *reinterpret_cast<const float4*>(src + col);
  float4 x1 = *reinterpret_cast<const float4*>(src + col + 4);
  half8 o = {(_Float16)x0.x, (_Float16)x0.y, (_Float16)x0.z, (_Float16)x0.w,
             (_Float16)x1.x, (_Float16)x1.y, (_Float16)x1.z, (_Float16)x1.w};
  *reinterpret_cast<half8*>(dst) = o;
}

// ---------------------------------------------------------------------------
// Kernel 2: fragment-direct MFMA projection. No LDS, no barriers.
// Each wave: one 32x32 tile; K-loop = 32 x (2 coalesced loads + 1 MFMA).
// Block = 4 waves covering 2 mt x 2 nt (L1 reuse of A and W panels).
// Epilogue writes Eq = 2^(C2*(pq+bias)), Ek = 2^(C2*pk).
// ---------------------------------------------------------------------------
__global__ __launch_bounds__(256) void mfma_proj_kernel(
    const _Float16* __restrict__ Afrag, const _Float16* __restrict__ Wkfrag,
    const _Float16* __restrict__ Wqfrag, const float* __restrict__ bias,
    float* __restrict__ Ek, float* __restrict__ Eq) {
  int bid = blockIdx.x;  // [0,576)
  int mblk = bid >> 3, nblk = bid & 7;
  int t = threadIdx.x, w = t >> 6, l = t & 63;
  int mt = mblk * 2 + (w >> 1);  // [0,144)
  int nt = nblk * 2 + (w & 1);   // [0,16)
  bool isQ = (mt >= 128);
  const _Float16* Wf = isQ ? Wqfrag : Wkfrag;
  const _Float16* ap = Afrag + ((size_t)mt * 32 * 64 + l) * 8;
  const _Float16* wp = Wf + ((size_t)nt * 32 * 64 + l) * 8;
  floatx16 acc;
#pragma unroll
  for (int i = 0; i < 16; i++) acc[i] = 0.f;
#pragma unroll 4
  for (int kc = 0; kc < 32; kc++) {
    half8 a = *reinterpret_cast<const half8*>(ap + (size_t)kc * 512);
    half8 wf = *reinterpret_cast<const half8*>(wp + (size_t)kc * 512);
    acc = __builtin_amdgcn_mfma_f32_32x32x16_f16(a, wf, acc, 0, 0, 0);
  }
  int col = nt * 32 + (l & 31);
  int g = l >> 5;
  float bv = isQ ? bias[col] : 0.f;
#pragma unroll
  for (int r = 0; r < 16; r++) {
    int row = mt * 32 + (r & 3) + 8 * (r >> 2) + 4 * g;
    float e = __builtin_amdgcn_exp2f((acc[r] + bv) * C2F);
    if (isQ)
      Eq[(size_t)(row - 4096) * NU_ + col] = e;
    else
      Ek[(size_t)row * NU_ + col] = e;
  }
}

// ---------------------------------------------------------------------------
// Fallback (ws too small): f32 projection writing Eq/Ek, + v kernel
// ---------------------------------------------------------------------------
__global__ __launch_bounds__(512) void compute_v_kernel(
    const float* __restrict__ la, const float* __restrict__ scalar,
    float* __restrict__ v) {
  __shared__ float red[8], red2[8];
  int t = threadIdx.x;
  float x = la[t];
  float ss = x * x;
#pragma unroll
  for (int o = 1; o < 64; o <<= 1) ss += __shfl_xor(ss, o, 64);
  int wave = t >> 6, lane = t & 63;
  if (lane == 0) red[wave] = ss;
  __syncthreads();
  float tot = 0.f;
#pragma unroll
  for (int w = 0; w < 8; w++) tot += red[w];
  float vv = x * rsqrtf(tot) * scalar[0];
  v[t] = vv;
  float sv = vv;
#pragma unroll
  for (int o = 1; o < 64; o <<= 1) sv += __shfl_xor(sv, o, 64);
  if (lane == 0) red2[wave] = sv;
  __syncthreads();
  if (t == 0) {
    float s = 0.f;
#pragma unroll
    for (int w = 0; w < 8; w++) s += red2[w];
    v[512] = s;
  }
}

__global__ __launch_bounds__(256) void proj_gemm_kernel(
    const float* __restrict__ query, const float* __restrict__ keys,
    const float* __restrict__ Wq, const float* __restrict__ Wk,
    const float* __restrict__ bias, float* __restrict__ Eq,
    float* __restrict__ Ek) {
  __shared__ __align__(16) float As[16][68];
  __shared__ __align__(16) float Bs[16][68];
  int mt = blockIdx.x;
  int n0 = blockIdx.y * 64;
  const float* A;
  const float* W;
  float* C;
  bool ub;
  if (mt < 8) {
    A = query + (size_t)mt * 64 * D_;
    W = Wq;
    C = Eq + (size_t)mt * 64 * NU_;
    ub = true;
  } else {
    A = keys + (size_t)(mt - 8) * 64 * D_;
    W = Wk;
    C = Ek + (size_t)(mt - 8) * 64 * NU_;
    ub = false;
  }
  int t = threadIdx.x;
  int tx = t & 15, ty = t >> 4;
  int ld = t & 15, lm = t >> 4;
  float acc[4][4] = {};
  for (int d0 = 0; d0 < D_; d0 += 16) {
#pragma unroll
    for (int r = 0; r < 4; r++) {
      As[ld][lm + 16 * r] = A[(size_t)(lm + 16 * r) * D_ + d0 + ld];
      Bs[ld][lm + 16 * r] = W[(size_t)(n0 + lm + 16 * r) * D_ + d0 + ld];
    }
    __syncthreads();
#pragma unroll
    for (int dd = 0; dd < 16; dd++) {
      float4 a4 = *reinterpret_cast<const float4*>(&As[dd][ty * 4]);
      float4 b4 = *reinterpret_cast<const float4*>(&Bs[dd][tx * 4]);
      float av[4] = {a4.x, a4.y, a4.z, a4.w};
      float bv[4] = {b4.x, b4.y, b4.z, b4.w};
#pragma unroll
      for (int i = 0; i < 4; i++)
#pragma unroll
        for (int j = 0; j < 4; j++)
          acc[i][j] = fmaf(av[i], bv[j], acc[i][j]);
    }
    __syncthreads();
  }
#pragma unroll
  for (int i = 0; i < 4; i++) {
    float4 o;
    float* op = &o.x;
#pragma unroll
    for (int j = 0; j < 4; j++) {
      float val = acc[i][j];
      if (ub) val += bias[n0 + tx * 4 + j];
      op[j] = __builtin_amdgcn_exp2f(val * C2F);
    }
    *reinterpret_cast<float4*>(&C[(size_t)(ty * 4 + i) * NU_ + n0 + tx * 4]) = o;
  }
}

// ---------------------------------------------------------------------------
// Kernel 3: scores. Block = (b, qtile 8, ktile 32). 256 thr.
// Wave pairs split u; each lane: 8 q x 2 k accumulators, 4-u slice.
// S[q,k] = vtot - 2 * sum_u v[u] / (1 + Eq[q,u]*Ek[k,u])
// ---------------------------------------------------------------------------
__global__ __launch_bounds__(256) void scores_kernel(
    const float* __restrict__ Eq, const float* __restrict__ Ek,
    const float* __restrict__ v, float* __restrict__ S) {
  __shared__ __align__(16) float sEq[8][NU_];  // 16 KB
  __shared__ __align__(16) float sV[NU_];      // 2 KB
  __shared__ float sRed[2][8][8][2];           // uw==1 partials: 1 KB
  int b = blockIdx.x >> 3, qt = blockIdx.x & 7, kt = blockIdx.y;
  int q0 = qt * 8, k0 = kt * 32;
  int t = threadIdx.x;
  const float4* eqsrc =
      reinterpret_cast<const float4*>(Eq + ((size_t)b * Q_ + q0) * NU_);
#pragma unroll
  for (int i = 0; i < 4; i++)
    reinterpret_cast<float4*>(&sEq[0][0])[t + 256 * i] = eqsrc[t + 256 * i];
  if (t < 128)
    reinterpret_cast<float4*>(sV)[t] = reinterpret_cast<const float4*>(v)[t];
  float vtot = v[512];
  __syncthreads();

  int wave = t >> 6, lane = t & 63;
  int uw = wave >> 1, kw = wave & 1;
  int klane = lane >> 3, ulane = lane & 7;
  int k = k0 + kw * 16 + klane * 2;
  int uh = uw * 256;
  const float* ek0p = Ek + ((size_t)b * K_ + k) * NU_;
  const float* ek1p = ek0p + NU_;
  float acc0[8] = {}, acc1[8] = {};
#pragma unroll 2
  for (int j = 0; j < 8; j++) {
    int u = uh + ulane * 4 + 32 * j;
    float4 e0 = *reinterpret_cast<const float4*>(ek0p + u);
    float4 e1 = *reinterpret_cast<const float4*>(ek1p + u);
    float4 v4 = *reinterpret_cast<const float4*>(&sV[u]);
    float e0v[4] = {e0.x, e0.y, e0.z, e0.w};
    float e1v[4] = {e1.x, e1.y, e1.z, e1.w};
    float vv[4] = {v4.x, v4.y, v4.z, v4.w};
#pragma unroll
    for (int qq = 0; qq < 8; qq++) {
      float4 q4 = *reinterpret_cast<const float4*>(&sEq[qq][u]);
      float qv[4] = {q4.x, q4.y, q4.z, q4.w};
#pragma unroll
      for (int i = 0; i < 4; i++) {
        float d0 = fmaf(qv[i], e0v[i], 1.f);
        float d1 = fmaf(qv[i], e1v[i], 1.f);
        acc0[qq] = fmaf(vv[i], __builtin_amdgcn_rcpf(d0), acc0[qq]);
        acc1[qq] = fmaf(vv[i], __builtin_amdgcn_rcpf(d1), acc1[qq]);
      }
    }
  }
#pragma unroll
  for (int qq = 0; qq < 8; qq++) {
    acc0[qq] += __shfl_xor(acc0[qq], 1, 64);
    acc0[qq] += __shfl_xor(acc0[qq], 2, 64);
    acc0[qq] += __shfl_xor(acc0[qq], 4, 64);
    acc1[qq] += __shfl_xor(acc1[qq], 1, 64);
    acc1[qq] += __shfl_xor(acc1[qq], 2, 64);
    acc1[qq] += __shfl_xor(acc1[qq], 4, 64);
  }
  if (uw == 1 && ulane == 0) {
#pragma unroll
    for (int qq = 0; qq < 8; qq++) {
      sRed[kw][klane][qq][0] = acc0[qq];
      sRed[kw][klane][qq][1] = acc1[qq];
    }
  }
  __syncthreads();
  if (uw == 0 && ulane == 0) {
#pragma unroll
    for (int qq = 0; qq < 8; qq++) {
      float a0 = acc0[qq] + sRed[kw][klane][qq][0];
      float a1 = acc1[qq] + sRed[kw][klane][qq][1];
      float* sp = S + ((size_t)b * Q_ + q0 + qq) * K_ + k;
      sp[0] = fmaf(-2.f, a0, vtot);
      sp[1] = fmaf(-2.f, a1, vtot);
    }
  }
}

// ---------------------------------------------------------------------------
// Kernel 4: softmax (dt==0) + context with q-register blocking.
// ---------------------------------------------------------------------------
__global__ __launch_bounds__(256) void ctx_kernel(
    const float* __restrict__ S, const float* __restrict__ keys,
    float* __restrict__ ctx, float* __restrict__ smx) {
  __shared__ __align__(16) float sS[8][K_];      // 16 KB
  __shared__ __align__(16) float sK[2][64][64];  // 32 KB
  __shared__ float sPart[3][32][16];             // 6 KB
  int b = blockIdx.x >> 3, qt = blockIdx.x & 7, dt = blockIdx.y;
  int q0 = qt * 8, d0 = dt * 64;
  int t = threadIdx.x;
  const float4* ssrc =
      reinterpret_cast<const float4*>(S + ((size_t)b * Q_ + q0) * K_);
#pragma unroll
  for (int i = 0; i < 4; i++)
    reinterpret_cast<float4*>(&sS[0][0])[t + 256 * i] = ssrc[t + 256 * i];
  const float* keysb = keys + (size_t)b * K_ * D_ + d0;
#pragma unroll
  for (int i = t; i < 1024; i += 256) {
    int row = i >> 4, c4 = i & 15;
    reinterpret_cast<float4*>(&sK[0][row][0])[c4] =
        *reinterpret_cast<const float4*>(&keysb[(size_t)row * D_ + c4 * 4]);
  }
  __syncthreads();

  {
    int q = t >> 5, lg = t & 31;
    float m = -1e30f;
    for (int kk = lg; kk < K_; kk += 32) m = fmaxf(m, sS[q][kk]);
#pragma unroll
    for (int o = 1; o < 32; o <<= 1) m = fmaxf(m, __shfl_xor(m, o, 64));
    const float L2E = 1.4426950408889634f;
    float sum = 0.f;
    for (int kk = lg; kk < K_; kk += 32)
      sum += __builtin_amdgcn_exp2f((sS[q][kk] - m) * L2E);
#pragma unroll
    for (int o = 1; o < 32; o <<= 1) sum += __shfl_xor(sum, o, 64);
    if (dt == 0) {
      float inv = 1.f / sum;
      float* dst = smx + ((size_t)b * Q_ + q0 + q) * K_;
      for (int kk = lg; kk < K_; kk += 32)
        dst[kk] = __builtin_amdgcn_exp2f((sS[q][kk] - m) * L2E) * inv;
    }
  }

  int dgroup = t & 31, ksplit = t >> 5;
  float acc[8][2] = {};
  int cur = 0;
  for (int kc = 0; kc < K_; kc += 64) {
    if (kc + 64 < K_) {
      const float* kn = keysb + (size_t)(kc + 64) * D_;
      for (int i = t; i < 1024; i += 256) {
        int row = i >> 4, c4 = i & 15;
        reinterpret_cast<float4*>(&sK[cur ^ 1][row][0])[c4] =
            *reinterpret_cast<const float4*>(&kn[(size_t)row * D_ + c4 * 4]);
      }
    }
#pragma unroll
    for (int i = 0; i < 8; i++) {
      int kk = ksplit * 8 + i;
      float2 kv = *reinterpret_cast<const float2*>(&sK[cur][kk][dgroup * 2]);
#pragma unroll
      for (int qq = 0; qq < 8; qq++) {
        float s = sS[qq][kc + kk];
        acc[qq][0] = fmaf(s, kv.x, acc[qq][0]);
        acc[qq][1] = fmaf(s, kv.y, acc[qq][1]);
      }
    }
    __syncthreads();
    cur ^= 1;
  }
  int wave = t >> 6, lane = t & 63;
#pragma unroll
  for (int qq = 0; qq < 8; qq++) {
    acc[qq][0] += __shfl_xor(acc[qq][0], 32, 64);
    acc[qq][1] += __shfl_xor(acc[qq][1], 32, 64);
  }
  if (wave > 0 && lane < 32) {
#pragma unroll
    for (int qq = 0; qq < 8; qq++) {
      sPart[wave - 1][lane][qq * 2] = acc[qq][0];
      sPart[wave - 1][lane][qq * 2 + 1] = acc[qq][1];
    }
  }
  __syncthreads();
  if (wave == 0 && lane < 32) {
#pragma unroll
    for (int qq = 0; qq < 8; qq++) {
      float c0 = acc[qq][0] + sPart[0][lane][qq * 2] +
                 sPart[1][lane][qq * 2] + sPart[2][lane][qq * 2];
      float c1 = acc[qq][1] + sPart[0][lane][qq * 2 + 1] +
                 sPart[1][lane][qq * 2 + 1] + sPart[2][lane][qq * 2 + 1];
      float2 o2 = {c0, c1};
      *reinterpret_cast<float2*>(
          &ctx[((size_t)b * Q_ + q0 + qq) * D_ + d0 + lane * 2]) = o2;
    }
  }
}

// ---------------------------------------------------------------------------
extern "C" void kernel_launch(void* const* d_in, const int* in_sizes, int n_in,
                              void* d_out, int out_size, void* d_ws,
                              size_t ws_size, hipStream_t stream) {
  const float* query = (const float*)d_in[0];
  const float* keys = (const float*)d_in[1];
  const float* Wq = (const float*)d_in[2];
  const float* Wk = (const float*)d_in[3];
  const float* la = (const float*)d_in[4];
  const float* nscalar = (const float*)d_in[5];
  const float* nbias = (const float*)d_in[6];

  float* out = (float*)d_out;
  float* ctx = out;
  float* smx = out + (size_t)B_ * Q_ * D_;

  float* ws = (float*)d_ws;
  float* v = ws + WS_V;
  float* Eq = ws + WS_EQ;
  float* Ek = ws + WS_EK;
  float* S = ws + WS_S;

  if (ws_size >= (size_t)WS_BYTES_MFMA) {
    _Float16* Afrag = (_Float16*)(ws + WS_FLOATS);
    _Float16* Wkfrag = Afrag + AH_ELEMS;
    _Float16* Wqfrag = Wkfrag + WH_ELEMS;
    convert_kernel<<<1409, 256, 0, stream>>>(query, keys, Wq, Wk, la, nscalar,
                                             Afrag, Wkfrag, Wqfrag, v);
    mfma_proj_kernel<<<576, 256, 0, stream>>>(Afrag, Wkfrag, Wqfrag, nbias, Ek,
                                              Eq);
  } else {
    compute_v_kernel<<<1, 512, 0, stream>>>(la, nscalar, v);
    proj_gemm_kernel<<<dim3(72, 8), 256, 0, stream>>>(query, keys, Wq, Wk,
                                                      nbias, Eq, Ek);
  }
  scores_kernel<<<dim3(64, 16), 256, 0, stream>>>(Eq, Ek, v, S);
  ctx_kernel<<<dim3(64, 8), 256, 0, stream>>>(S, keys, ctx, smx);
}

// Round 7
// 58.687 us; speedup vs baseline: 1.0056x; 1.0056x over previous
//
#include <hip/hip_runtime.h>

#define B_ 8
#define Q_ 64
#define K_ 512
#define NU_ 512
#define D_ 512

typedef __attribute__((ext_vector_type(8))) _Float16 half8;
typedef __attribute__((ext_vector_type(4))) _Float16 half4;
typedef __attribute__((ext_vector_type(16))) float floatx16;

#define C2F 2.8853900817779268f  // 2*log2(e)

// ws float-layout (10.5 MB total; harness ws is ~268 MB)
#define WS_V 0                   // v[0..511], vtot at [512]
#define WS_EQ 640                // Eq: 8*64*512
#define WS_EK (640 + 262144)     // Ek: 8*512*512
#define WS_S (WS_EK + 2097152)   // S raw scores: 8*64*512

// ---------------------------------------------------------------------------
// Kernel 1: MFMA projection reading f32 inputs directly (inline cvt to f16
// during LDS staging). Flattened row space: rows 0..4095 = keys -> Ek,
// rows 4096..4607 = query -> Eq (+bias). Epilogue: E = 2^(C2*(proj[+bias])).
// blockIdx.x == 72 (y==0): computes v = normalize(linear_att)*scalar, vtot.
// ---------------------------------------------------------------------------
__global__ __launch_bounds__(256) void proj_kernel(
    const float* __restrict__ query, const float* __restrict__ keys,
    const float* __restrict__ Wq, const float* __restrict__ Wk,
    const float* __restrict__ la, const float* __restrict__ scalar,
    const float* __restrict__ bias, float* __restrict__ Ek,
    float* __restrict__ Eq, float* __restrict__ v) {
  int t = threadIdx.x;
  if (blockIdx.x == 72) {
    if (blockIdx.y != 0) return;
    __shared__ float red[4], red2[4];
    float x0 = la[t], x1 = la[t + 256];
    float ss = x0 * x0 + x1 * x1;
#pragma unroll
    for (int o = 1; o < 64; o <<= 1) ss += __shfl_xor(ss, o, 64);
    int wave = t >> 6, lane = t & 63;
    if (lane == 0) red[wave] = ss;
    __syncthreads();
    float tot = red[0] + red[1] + red[2] + red[3];
    float sc = rsqrtf(tot) * scalar[0];
    float v0 = x0 * sc, v1 = x1 * sc;
    v[t] = v0;
    v[t + 256] = v1;
    float sv = v0 + v1;
#pragma unroll
    for (int o = 1; o < 64; o <<= 1) sv += __shfl_xor(sv, o, 64);
    if (lane == 0) red2[wave] = sv;
    __syncthreads();
    if (t == 0) v[512] = red2[0] + red2[1] + red2[2] + red2[3];
    return;
  }

  __shared__ _Float16 sA[64][72];  // 144B row stride
  __shared__ _Float16 sW[64][72];
  int m0 = blockIdx.x * 64, n0 = blockIdx.y * 64;
  bool isQ = (m0 >= 4096);
  const float* Abase =
      isQ ? query + (size_t)(m0 - 4096) * D_ : keys + (size_t)m0 * D_;
  const float* Wbase = (isQ ? Wq : Wk) + (size_t)n0 * D_;
  // staging coords: 4 passes of (16 rows x 64 cols), 4 f32 per thread per pass
  int lrow = t >> 4;          // 0..15
  int lcol = (t & 15) * 4;    // 0..60
  int wave = t >> 6, lane = t & 63;
  int mw = (wave >> 1) * 32, nw = (wave & 1) * 32;
  int lr = lane & 31, g = lane >> 5;

  half4 pa[4], pw[4];
#pragma unroll
  for (int p = 0; p < 4; p++) {
    float4 xa = *reinterpret_cast<const float4*>(
        Abase + (size_t)(lrow + 16 * p) * D_ + lcol);
    float4 xw = *reinterpret_cast<const float4*>(
        Wbase + (size_t)(lrow + 16 * p) * D_ + lcol);
    pa[p] = half4{(_Float16)xa.x, (_Float16)xa.y, (_Float16)xa.z,
                  (_Float16)xa.w};
    pw[p] = half4{(_Float16)xw.x, (_Float16)xw.y, (_Float16)xw.z,
                  (_Float16)xw.w};
  }
  floatx16 acc;
#pragma unroll
  for (int i = 0; i < 16; i++) acc[i] = 0.f;
  for (int k0 = 0; k0 < 512; k0 += 64) {
    __syncthreads();  // previous iteration's fragment reads complete
#pragma unroll
    for (int p = 0; p < 4; p++) {
      *reinterpret_cast<half4*>(&sA[lrow + 16 * p][lcol]) = pa[p];
      *reinterpret_cast<half4*>(&sW[lrow + 16 * p][lcol]) = pw[p];
    }
    if (k0 + 64 < 512) {
#pragma unroll
      for (int p = 0; p < 4; p++) {
        float4 xa = *reinterpret_cast<const float4*>(
            Abase + (size_t)(lrow + 16 * p) * D_ + k0 + 64 + lcol);
        float4 xw = *reinterpret_cast<const float4*>(
            Wbase + (size_t)(lrow + 16 * p) * D_ + k0 + 64 + lcol);
        pa[p] = half4{(_Float16)xa.x, (_Float16)xa.y, (_Float16)xa.z,
                      (_Float16)xa.w};
        pw[p] = half4{(_Float16)xw.x, (_Float16)xw.y, (_Float16)xw.z,
                      (_Float16)xw.w};
      }
    }
    __syncthreads();  // LDS ready
#pragma unroll
    for (int i = 0; i < 4; i++) {
      half8 af = *reinterpret_cast<const half8*>(&sA[mw + lr][i * 16 + g * 8]);
      half8 wf = *reinterpret_cast<const half8*>(&sW[nw + lr][i * 16 + g * 8]);
      acc = __builtin_amdgcn_mfma_f32_32x32x16_f16(af, wf, acc, 0, 0, 0);
    }
  }
  int col = n0 + nw + lr;
  float bv = isQ ? bias[col] : 0.f;
#pragma unroll
  for (int r = 0; r < 16; r++) {
    int row = m0 + mw + (r & 3) + 8 * (r >> 2) + 4 * g;
    float e = __builtin_amdgcn_exp2f((acc[r] + bv) * C2F);
    if (isQ)
      Eq[(size_t)(row - 4096) * NU_ + col] = e;
    else
      Ek[(size_t)row * NU_ + col] = e;
  }
}

// ---------------------------------------------------------------------------
// Kernel 2: scores. Block = (b, qtile 8, ktile 16). 256 thr.
// 4 waves: uw = wave>>1 (u half), kw = wave&1 (k half of 16).
// Lane: klane = lane>>3 (1 k), ulane = lane&7 (4-float u slice), 8 q accs.
// Pairwise rational combine: v0/p0 + v1/p1 = (v0*p1 + v1*p0) / (p0*p1),
// p = 1 + Eq*Ek  ->  1 rcp per 2 u-terms.
// S[q,k] = vtot - 2 * sum_u v[u] / (1 + Eq[q,u]*Ek[k,u])
// ---------------------------------------------------------------------------
__global__ __launch_bounds__(256) void scores_kernel(
    const float* __restrict__ Eq, const float* __restrict__ Ek,
    const float* __restrict__ v, float* __restrict__ S) {
  __shared__ __align__(16) float sEq[8][NU_];  // 16 KB
  __shared__ __align__(16) float sV[NU_];      // 2 KB
  __shared__ float sRed[2][8][8];              // 512 B
  int b = blockIdx.x >> 3, qt = blockIdx.x & 7, kt = blockIdx.y;
  int q0 = qt * 8, k0 = kt * 16;
  int t = threadIdx.x;
  const float4* eqsrc =
      reinterpret_cast<const float4*>(Eq + ((size_t)b * Q_ + q0) * NU_);
#pragma unroll
  for (int i = 0; i < 4; i++)
    reinterpret_cast<float4*>(&sEq[0][0])[t + 256 * i] = eqsrc[t + 256 * i];
  if (t < 128)
    reinterpret_cast<float4*>(sV)[t] = reinterpret_cast<const float4*>(v)[t];
  float vtot = v[512];
  __syncthreads();

  int wave = t >> 6, lane = t & 63;
  int uw = wave >> 1, kw = wave & 1;
  int klane = lane >> 3, ulane = lane & 7;
  int k = k0 + kw * 8 + klane;
  const float* ekr = Ek + ((size_t)b * K_ + k) * NU_;
  float acc[8] = {};
#pragma unroll 2
  for (int j = 0; j < 8; j++) {
    int u = uw * 256 + ulane * 4 + 32 * j;
    float4 ek4 = *reinterpret_cast<const float4*>(ekr + u);
    float4 v4 = *reinterpret_cast<const float4*>(&sV[u]);
#pragma unroll
    for (int qq = 0; qq < 8; qq++) {
      float4 eq4 = *reinterpret_cast<const float4*>(&sEq[qq][u]);
      float p0 = fmaf(eq4.x, ek4.x, 1.f);
      float p1 = fmaf(eq4.y, ek4.y, 1.f);
      float p2 = fmaf(eq4.z, ek4.z, 1.f);
      float p3 = fmaf(eq4.w, ek4.w, 1.f);
      float n01 = fmaf(v4.x, p1, v4.y * p0);
      float n23 = fmaf(v4.z, p3, v4.w * p2);
      float r01 = __builtin_amdgcn_rcpf(p0 * p1);
      float r23 = __builtin_amdgcn_rcpf(p2 * p3);
      acc[qq] = fmaf(n01, r01, acc[qq]);
      acc[qq] = fmaf(n23, r23, acc[qq]);
    }
  }
#pragma unroll
  for (int qq = 0; qq < 8; qq++) {
    acc[qq] += __shfl_xor(acc[qq], 1, 64);
    acc[qq] += __shfl_xor(acc[qq], 2, 64);
    acc[qq] += __shfl_xor(acc[qq], 4, 64);
  }
  if (uw == 1 && ulane == 0) {
#pragma unroll
    for (int qq = 0; qq < 8; qq++) sRed[kw][klane][qq] = acc[qq];
  }
  __syncthreads();
  if (uw == 0 && ulane == 0) {
#pragma unroll
    for (int qq = 0; qq < 8; qq++) {
      float a = acc[qq] + sRed[kw][klane][qq];
      S[((size_t)b * Q_ + q0 + qq) * K_ + k] = fmaf(-2.f, a, vtot);
    }
  }
}

// ---------------------------------------------------------------------------
// Kernel 3: softmax (dt==0 writes smx) + context. Block = (b, qtile 8,
// dtile 32). 256 thr: dg = t&15 (2 d's), ks = t>>4 (16-way k-split).
// LDS 36 KB -> 4 blocks/CU.
// ---------------------------------------------------------------------------
__global__ __launch_bounds__(256) void ctx_kernel(
    const float* __restrict__ S, const float* __restrict__ keys,
    float* __restrict__ ctx, float* __restrict__ smx) {
  __shared__ __align__(16) float sS[8][K_];      // 16 KB
  __shared__ __align__(16) float sK[2][64][32];  // 16 KB
  __shared__ float sPart[3][16][16];             // 3 KB
  int b = blockIdx.x >> 3, qt = blockIdx.x & 7, dt = blockIdx.y;
  int q0 = qt * 8, d0 = dt * 32;
  int t = threadIdx.x;
  const float4* ssrc =
      reinterpret_cast<const float4*>(S + ((size_t)b * Q_ + q0) * K_);
#pragma unroll
  for (int i = 0; i < 4; i++)
    reinterpret_cast<float4*>(&sS[0][0])[t + 256 * i] = ssrc[t + 256 * i];
  const float* keysb = keys + (size_t)b * K_ * D_ + d0;
#pragma unroll
  for (int e = 0; e < 2; e++) {
    int idx = t * 2 + e;
    int row = idx >> 3, c4 = idx & 7;
    *reinterpret_cast<float4*>(&sK[0][row][c4 * 4]) =
        *reinterpret_cast<const float4*>(&keysb[(size_t)row * D_ + c4 * 4]);
  }
  __syncthreads();

  // ---- softmax (32-lane group per q) ----
  {
    int q = t >> 5, lg = t & 31;
    float m = -1e30f;
    for (int kk = lg; kk < K_; kk += 32) m = fmaxf(m, sS[q][kk]);
#pragma unroll
    for (int o = 1; o < 32; o <<= 1) m = fmaxf(m, __shfl_xor(m, o, 64));
    const float L2E = 1.4426950408889634f;
    float sum = 0.f;
    for (int kk = lg; kk < K_; kk += 32)
      sum += __builtin_amdgcn_exp2f((sS[q][kk] - m) * L2E);
#pragma unroll
    for (int o = 1; o < 32; o <<= 1) sum += __shfl_xor(sum, o, 64);
    if (dt == 0) {
      float inv = 1.f / sum;
      float* dst = smx + ((size_t)b * Q_ + q0 + q) * K_;
      for (int kk = lg; kk < K_; kk += 32)
        dst[kk] = __builtin_amdgcn_exp2f((sS[q][kk] - m) * L2E) * inv;
    }
  }

  // ---- context: acc[8q][2d] per thread, 16-way k-split ----
  int dg = t & 15, ks = t >> 4;
  float acc[8][2] = {};
  int cur = 0;
  for (int kc = 0; kc < K_; kc += 64) {
    if (kc + 64 < K_) {
      const float* kn = keysb + (size_t)(kc + 64) * D_;
#pragma unroll
      for (int e = 0; e < 2; e++) {
        int idx = t * 2 + e;
        int row = idx >> 3, c4 = idx & 7;
        *reinterpret_cast<float4*>(&sK[cur ^ 1][row][c4 * 4]) =
            *reinterpret_cast<const float4*>(&kn[(size_t)row * D_ + c4 * 4]);
      }
    }
#pragma unroll
    for (int i = 0; i < 4; i++) {
      int kk = ks * 4 + i;
      float2 kv = *reinterpret_cast<const float2*>(&sK[cur][kk][dg * 2]);
#pragma unroll
      for (int qq = 0; qq < 8; qq++) {
        float s = sS[qq][kc + kk];
        acc[qq][0] = fmaf(s, kv.x, acc[qq][0]);
        acc[qq][1] = fmaf(s, kv.y, acc[qq][1]);
      }
    }
    __syncthreads();
    cur ^= 1;
  }
  // reduce over ks: bits 4,5 within wave, then across 4 waves via LDS
  int wave = t >> 6, lane = t & 63;
#pragma unroll
  for (int qq = 0; qq < 8; qq++) {
    acc[qq][0] += __shfl_xor(acc[qq][0], 16, 64);
    acc[qq][1] += __shfl_xor(acc[qq][1], 16, 64);
    acc[qq][0] += __shfl_xor(acc[qq][0], 32, 64);
    acc[qq][1] += __shfl_xor(acc[qq][1], 32, 64);
  }
  if (wave > 0 && lane < 16) {
#pragma unroll
    for (int qq = 0; qq < 8; qq++) {
      sPart[wave - 1][lane][qq * 2] = acc[qq][0];
      sPart[wave - 1][lane][qq * 2 + 1] = acc[qq][1];
    }
  }
  __syncthreads();
  if (wave == 0 && lane < 16) {
#pragma unroll
    for (int qq = 0; qq < 8; qq++) {
      float c0 = acc[qq][0] + sPart[0][lane][qq * 2] +
                 sPart[1][lane][qq * 2] + sPart[2][lane][qq * 2];
      float c1 = acc[qq][1] + sPart[0][lane][qq * 2 + 1] +
                 sPart[1][lane][qq * 2 + 1] + sPart[2][lane][qq * 2 + 1];
      float2 o2 = {c0, c1};
      *reinterpret_cast<float2*>(
          &ctx[((size_t)b * Q_ + q0 + qq) * D_ + d0 + lane * 2]) = o2;
    }
  }
}

// ---------------------------------------------------------------------------
extern "C" void kernel_launch(void* const* d_in, const int* in_sizes, int n_in,
                              void* d_out, int out_size, void* d_ws,
                              size_t ws_size, hipStream_t stream) {
  const float* query = (const float*)d_in[0];
  const float* keys = (const float*)d_in[1];
  const float* Wq = (const float*)d_in[2];
  const float* Wk = (const float*)d_in[3];
  const float* la = (const float*)d_in[4];
  const float* nscalar = (const float*)d_in[5];
  const float* nbias = (const float*)d_in[6];

  float* out = (float*)d_out;
  float* ctx = out;
  float* smx = out + (size_t)B_ * Q_ * D_;

  float* ws = (float*)d_ws;
  float* v = ws + WS_V;
  float* Eq = ws + WS_EQ;
  float* Ek = ws + WS_EK;
  float* S = ws + WS_S;

  proj_kernel<<<dim3(73, 8), 256, 0, stream>>>(query, keys, Wq, Wk, la,
                                               nscalar, nbias, Ek, Eq, v);
  scores_kernel<<<dim3(64, 32), 256, 0, stream>>>(Eq, Ek, v, S);
  ctx_kernel<<<dim3(64, 16), 256, 0, stream>>>(S, keys, ctx, smx);
}

// Round 8
// 56.619 us; speedup vs baseline: 1.0423x; 1.0365x over previous
//
#include <hip/hip_runtime.h>

#define B_ 8
#define Q_ 64
#define K_ 512
#define NU_ 512
#define D_ 512

typedef __attribute__((ext_vector_type(8))) _Float16 half8;
typedef __attribute__((ext_vector_type(4))) _Float16 half4;
typedef __attribute__((ext_vector_type(16))) float floatx16;

#define C2F 2.8853900817779268f  // 2*log2(e)

// ws float-layout
#define WS_V 0                   // v[0..511], vtot at [512]
#define WS_EQ 640                // Eq: 8*64*512
#define WS_EK (640 + 262144)     // Ek: 8*512*512
#define WS_S (WS_EK + 2097152)   // S raw scores: 8*64*512
#define WS_FLOATS (WS_S + 262144)
#define AH_ELEMS 2359296         // 4608*512 f16 (keys rows 0..4095, query 4096..4607)
#define WH_ELEMS 262144          // 512*512 f16
#define WS_BYTES_MFMA (WS_FLOATS * 4 + (size_t)(AH_ELEMS + 2 * WH_ELEMS) * 2)

#define GLD16(gp, lp)                                                         \
  __builtin_amdgcn_global_load_lds(                                           \
      (const __attribute__((address_space(1))) void*)(gp),                    \
      (__attribute__((address_space(3))) void*)(lp), 16, 0, 0)

// ---------------------------------------------------------------------------
// Kernel 1: f32 -> f16 convert into PRE-SWIZZLED row-major layout + v.
// Out[row*512 + bb*8 + j] = In[row][ ((bb&56) | ((bb^row)&7))*8 + j ]
// (16B blocks XOR'd with row&7 within each 128B K-slab) so that a LINEAR
// global_load_lds copy yields an LDS tile readable with the same XOR.
// Blocks: A 1152, Wk 128, Wq 128, v 1 -> 1409.
// ---------------------------------------------------------------------------
__global__ __launch_bounds__(256) void convert_kernel(
    const float* __restrict__ query, const float* __restrict__ keys,
    const float* __restrict__ Wq, const float* __restrict__ Wk,
    const float* __restrict__ la, const float* __restrict__ scalar,
    _Float16* __restrict__ Acvt, _Float16* __restrict__ Wkcvt,
    _Float16* __restrict__ Wqcvt, float* __restrict__ v) {
  int bid = blockIdx.x;
  int t = threadIdx.x;
  if (bid == 1408) {  // v block
    __shared__ float red[4], red2[4];
    float x0 = la[t], x1 = la[t + 256];
    float ss = x0 * x0 + x1 * x1;
#pragma unroll
    for (int o = 1; o < 64; o <<= 1) ss += __shfl_xor(ss, o, 64);
    int wave = t >> 6, lane = t & 63;
    if (lane == 0) red[wave] = ss;
    __syncthreads();
    float tot = red[0] + red[1] + red[2] + red[3];
    float sc = rsqrtf(tot) * scalar[0];
    float v0 = x0 * sc, v1 = x1 * sc;
    v[t] = v0;
    v[t + 256] = v1;
    float sv = v0 + v1;
#pragma unroll
    for (int o = 1; o < 64; o <<= 1) sv += __shfl_xor(sv, o, 64);
    if (lane == 0) red2[wave] = sv;
    __syncthreads();
    if (t == 0) v[512] = red2[0] + red2[1] + red2[2] + red2[3];
    return;
  }
  const float* src;
  _Float16* dst;
  int row, bb;
  if (bid < 1152) {  // A: rows<4096 keys, else query
    int tid = bid * 256 + t;
    row = tid >> 6;
    bb = tid & 63;
    src = (row < 4096) ? keys + (size_t)row * 512
                       : query + (size_t)(row - 4096) * 512;
    dst = Acvt + (size_t)row * 512;
  } else if (bid < 1280) {
    int tid = (bid - 1152) * 256 + t;
    row = tid >> 6;
    bb = tid & 63;
    src = Wk + (size_t)row * 512;
    dst = Wkcvt + (size_t)row * 512;
  } else {
    int tid = (bid - 1280) * 256 + t;
    row = tid >> 6;
    bb = tid & 63;
    src = Wq + (size_t)row * 512;
    dst = Wqcvt + (size_t)row * 512;
  }
  int scol = ((bb & 56) | ((bb ^ row) & 7)) * 8;
  float4 x0 = *reinterpret_cast<const float4*>(src + scol);
  float4 x1 = *reinterpret_cast<const float4*>(src + scol + 4);
  half8 o = {(_Float16)x0.x, (_Float16)x0.y, (_Float16)x0.z, (_Float16)x0.w,
             (_Float16)x1.x, (_Float16)x1.y, (_Float16)x1.z, (_Float16)x1.w};
  *reinterpret_cast<half8*>(dst + bb * 8) = o;
}

// ---------------------------------------------------------------------------
// Kernel 2: MFMA projection, global_load_lds staging, double-buffered LDS,
// XOR-swizzled fragment reads. 64x64 tile, K-step 64, one barrier per step.
// Epilogue writes Eq = 2^(C2*(pq+bias)), Ek = 2^(C2*pk).
// ---------------------------------------------------------------------------
__global__ __launch_bounds__(256) void mfma_proj_kernel(
    const _Float16* __restrict__ Acvt, const _Float16* __restrict__ Wkcvt,
    const _Float16* __restrict__ Wqcvt, const float* __restrict__ bias,
    float* __restrict__ Ek, float* __restrict__ Eq) {
  __shared__ _Float16 sA[2][64][64];  // 16 KB (linear, pre-swizzled source)
  __shared__ _Float16 sW[2][64][64];  // 16 KB
  int m0 = blockIdx.x * 64, n0 = blockIdx.y * 64;
  bool isQ = (m0 >= 4096);
  const _Float16* Wcvt = isQ ? Wqcvt : Wkcvt;
  int t = threadIdx.x;
  int wave = t >> 6, lane = t & 63;
  int mw = (wave >> 1) * 32, nw = (wave & 1) * 32;
  int lr = lane & 31, g = lane >> 5;
  int arow = mw + lr, wrow = nw + lr;
  // G2L lane source offsets: region r covers rows r*8..r*8+7
  int lrow = lane >> 3, lblk = lane & 7;  // within a region
  const _Float16* gAbase =
      Acvt + ((size_t)(m0 + wave * 16 + lrow)) * 512 + lblk * 8;
  const _Float16* gWbase =
      Wcvt + ((size_t)(n0 + wave * 16 + lrow)) * 512 + lblk * 8;

  floatx16 acc;
#pragma unroll
  for (int i = 0; i < 16; i++) acc[i] = 0.f;

  // stage(t, sel): wave stages regions {2w, 2w+1} (16 rows) of A and W
#define STAGE(kt, sel)                                                        \
  {                                                                           \
    int koff = (kt)*64;                                                       \
    GLD16(gAbase + koff, &sA[sel][wave * 16][0]);                             \
    GLD16(gAbase + koff + 8 * 512, &sA[sel][wave * 16 + 8][0]);               \
    GLD16(gWbase + koff, &sW[sel][wave * 16][0]);                             \
    GLD16(gWbase + koff + 8 * 512, &sW[sel][wave * 16 + 8][0]);               \
  }

  STAGE(0, 0);
  for (int kt = 0; kt < 8; kt++) {
    __syncthreads();  // drains this wave's G2L (compiler full-drain) + sync
    if (kt < 7) STAGE(kt + 1, (kt + 1) & 1);
    int sel = kt & 1;
#pragma unroll
    for (int i = 0; i < 4; i++) {
      int ablk = (((2 * i + g) ^ arow) & 7) * 8 + ((2 * i + g) & ~7) * 8;
      int wblk = (((2 * i + g) ^ wrow) & 7) * 8 + ((2 * i + g) & ~7) * 8;
      half8 af = *reinterpret_cast<const half8*>(&sA[sel][arow][ablk]);
      half8 wf = *reinterpret_cast<const half8*>(&sW[sel][wrow][wblk]);
      acc = __builtin_amdgcn_mfma_f32_32x32x16_f16(af, wf, acc, 0, 0, 0);
    }
  }
#undef STAGE
  int col = n0 + nw + lr;
  float bv = isQ ? bias[col] : 0.f;
#pragma unroll
  for (int r = 0; r < 16; r++) {
    int row = m0 + mw + (r & 3) + 8 * (r >> 2) + 4 * g;
    float e = __builtin_amdgcn_exp2f((acc[r] + bv) * C2F);
    if (isQ)
      Eq[(size_t)(row - 4096) * NU_ + col] = e;
    else
      Ek[(size_t)row * NU_ + col] = e;
  }
}

// ---------------------------------------------------------------------------
// Fallback (ws too small): f32 projection writing Eq/Ek, + v kernel
// ---------------------------------------------------------------------------
__global__ __launch_bounds__(512) void compute_v_kernel(
    const float* __restrict__ la, const float* __restrict__ scalar,
    float* __restrict__ v) {
  __shared__ float red[8], red2[8];
  int t = threadIdx.x;
  float x = la[t];
  float ss = x * x;
#pragma unroll
  for (int o = 1; o < 64; o <<= 1) ss += __shfl_xor(ss, o, 64);
  int wave = t >> 6, lane = t & 63;
  if (lane == 0) red[wave] = ss;
  __syncthreads();
  float tot = 0.f;
#pragma unroll
  for (int w = 0; w < 8; w++) tot += red[w];
  float vv = x * rsqrtf(tot) * scalar[0];
  v[t] = vv;
  float sv = vv;
#pragma unroll
  for (int o = 1; o < 64; o <<= 1) sv += __shfl_xor(sv, o, 64);
  if (lane == 0) red2[wave] = sv;
  __syncthreads();
  if (t == 0) {
    float s = 0.f;
#pragma unroll
    for (int w = 0; w < 8; w++) s += red2[w];
    v[512] = s;
  }
}

__global__ __launch_bounds__(256) void proj_gemm_kernel(
    const float* __restrict__ query, const float* __restrict__ keys,
    const float* __restrict__ Wq, const float* __restrict__ Wk,
    const float* __restrict__ bias, float* __restrict__ Eq,
    float* __restrict__ Ek) {
  __shared__ __align__(16) float As[16][68];
  __shared__ __align__(16) float Bs[16][68];
  int mt = blockIdx.x;
  int n0 = blockIdx.y * 64;
  const float* A;
  const float* W;
  float* C;
  bool ub;
  if (mt < 8) {
    A = query + (size_t)mt * 64 * D_;
    W = Wq;
    C = Eq + (size_t)mt * 64 * NU_;
    ub = true;
  } else {
    A = keys + (size_t)(mt - 8) * 64 * D_;
    W = Wk;
    C = Ek + (size_t)(mt - 8) * 64 * NU_;
    ub = false;
  }
  int t = threadIdx.x;
  int tx = t & 15, ty = t >> 4;
  int ld = t & 15, lm = t >> 4;
  float acc[4][4] = {};
  for (int d0 = 0; d0 < D_; d0 += 16) {
#pragma unroll
    for (int r = 0; r < 4; r++) {
      As[ld][lm + 16 * r] = A[(size_t)(lm + 16 * r) * D_ + d0 + ld];
      Bs[ld][lm + 16 * r] = W[(size_t)(n0 + lm + 16 * r) * D_ + d0 + ld];
    }
    __syncthreads();
#pragma unroll
    for (int dd = 0; dd < 16; dd++) {
      float4 a4 = *reinterpret_cast<const float4*>(&As[dd][ty * 4]);
      float4 b4 = *reinterpret_cast<const float4*>(&Bs[dd][tx * 4]);
      float av[4] = {a4.x, a4.y, a4.z, a4.w};
      float bv[4] = {b4.x, b4.y, b4.z, b4.w};
#pragma unroll
      for (int i = 0; i < 4; i++)
#pragma unroll
        for (int j = 0; j < 4; j++)
          acc[i][j] = fmaf(av[i], bv[j], acc[i][j]);
    }
    __syncthreads();
  }
#pragma unroll
  for (int i = 0; i < 4; i++) {
    float4 o;
    float* op = &o.x;
#pragma unroll
    for (int j = 0; j < 4; j++) {
      float val = acc[i][j];
      if (ub) val += bias[n0 + tx * 4 + j];
      op[j] = __builtin_amdgcn_exp2f(val * C2F);
    }
    *reinterpret_cast<float4*>(&C[(size_t)(ty * 4 + i) * NU_ + n0 + tx * 4]) = o;
  }
}

// ---------------------------------------------------------------------------
// Kernel 3: scores (UNCHANGED from round 7).
// ---------------------------------------------------------------------------
__global__ __launch_bounds__(256) void scores_kernel(
    const float* __restrict__ Eq, const float* __restrict__ Ek,
    const float* __restrict__ v, float* __restrict__ S) {
  __shared__ __align__(16) float sEq[8][NU_];  // 16 KB
  __shared__ __align__(16) float sV[NU_];      // 2 KB
  __shared__ float sRed[2][8][8];              // 512 B
  int b = blockIdx.x >> 3, qt = blockIdx.x & 7, kt = blockIdx.y;
  int q0 = qt * 8, k0 = kt * 16;
  int t = threadIdx.x;
  const float4* eqsrc =
      reinterpret_cast<const float4*>(Eq + ((size_t)b * Q_ + q0) * NU_);
#pragma unroll
  for (int i = 0; i < 4; i++)
    reinterpret_cast<float4*>(&sEq[0][0])[t + 256 * i] = eqsrc[t + 256 * i];
  if (t < 128)
    reinterpret_cast<float4*>(sV)[t] = reinterpret_cast<const float4*>(v)[t];
  float vtot = v[512];
  __syncthreads();

  int wave = t >> 6, lane = t & 63;
  int uw = wave >> 1, kw = wave & 1;
  int klane = lane >> 3, ulane = lane & 7;
  int k = k0 + kw * 8 + klane;
  const float* ekr = Ek + ((size_t)b * K_ + k) * NU_;
  float acc[8] = {};
#pragma unroll 2
  for (int j = 0; j < 8; j++) {
    int u = uw * 256 + ulane * 4 + 32 * j;
    float4 ek4 = *reinterpret_cast<const float4*>(ekr + u);
    float4 v4 = *reinterpret_cast<const float4*>(&sV[u]);
#pragma unroll
    for (int qq = 0; qq < 8; qq++) {
      float4 eq4 = *reinterpret_cast<const float4*>(&sEq[qq][u]);
      float p0 = fmaf(eq4.x, ek4.x, 1.f);
      float p1 = fmaf(eq4.y, ek4.y, 1.f);
      float p2 = fmaf(eq4.z, ek4.z, 1.f);
      float p3 = fmaf(eq4.w, ek4.w, 1.f);
      float n01 = fmaf(v4.x, p1, v4.y * p0);
      float n23 = fmaf(v4.z, p3, v4.w * p2);
      float r01 = __builtin_amdgcn_rcpf(p0 * p1);
      float r23 = __builtin_amdgcn_rcpf(p2 * p3);
      acc[qq] = fmaf(n01, r01, acc[qq]);
      acc[qq] = fmaf(n23, r23, acc[qq]);
    }
  }
#pragma unroll
  for (int qq = 0; qq < 8; qq++) {
    acc[qq] += __shfl_xor(acc[qq], 1, 64);
    acc[qq] += __shfl_xor(acc[qq], 2, 64);
    acc[qq] += __shfl_xor(acc[qq], 4, 64);
  }
  if (uw == 1 && ulane == 0) {
#pragma unroll
    for (int qq = 0; qq < 8; qq++) sRed[kw][klane][qq] = acc[qq];
  }
  __syncthreads();
  if (uw == 0 && ulane == 0) {
#pragma unroll
    for (int qq = 0; qq < 8; qq++) {
      float a = acc[qq] + sRed[kw][klane][qq];
      S[((size_t)b * Q_ + q0 + qq) * K_ + k] = fmaf(-2.f, a, vtot);
    }
  }
}

// ---------------------------------------------------------------------------
// Kernel 4: softmax + context (UNCHANGED from round 7).
// ---------------------------------------------------------------------------
__global__ __launch_bounds__(256) void ctx_kernel(
    const float* __restrict__ S, const float* __restrict__ keys,
    float* __restrict__ ctx, float* __restrict__ smx) {
  __shared__ __align__(16) float sS[8][K_];      // 16 KB
  __shared__ __align__(16) float sK[2][64][32];  // 16 KB
  __shared__ float sPart[3][16][16];             // 3 KB
  int b = blockIdx.x >> 3, qt = blockIdx.x & 7, dt = blockIdx.y;
  int q0 = qt * 8, d0 = dt * 32;
  int t = threadIdx.x;
  const float4* ssrc =
      reinterpret_cast<const float4*>(S + ((size_t)b * Q_ + q0) * K_);
#pragma unroll
  for (int i = 0; i < 4; i++)
    reinterpret_cast<float4*>(&sS[0][0])[t + 256 * i] = ssrc[t + 256 * i];
  const float* keysb = keys + (size_t)b * K_ * D_ + d0;
#pragma unroll
  for (int e = 0; e < 2; e++) {
    int idx = t * 2 + e;
    int row = idx >> 3, c4 = idx & 7;
    *reinterpret_cast<float4*>(&sK[0][row][c4 * 4]) =
        *reinterpret_cast<const float4*>(&keysb[(size_t)row * D_ + c4 * 4]);
  }
  __syncthreads();

  {
    int q = t >> 5, lg = t & 31;
    float m = -1e30f;
    for (int kk = lg; kk < K_; kk += 32) m = fmaxf(m, sS[q][kk]);
#pragma unroll
    for (int o = 1; o < 32; o <<= 1) m = fmaxf(m, __shfl_xor(m, o, 64));
    const float L2E = 1.4426950408889634f;
    float sum = 0.f;
    for (int kk = lg; kk < K_; kk += 32)
      sum += __builtin_amdgcn_exp2f((sS[q][kk] - m) * L2E);
#pragma unroll
    for (int o = 1; o < 32; o <<= 1) sum += __shfl_xor(sum, o, 64);
    if (dt == 0) {
      float inv = 1.f / sum;
      float* dst = smx + ((size_t)b * Q_ + q0 + q) * K_;
      for (int kk = lg; kk < K_; kk += 32)
        dst[kk] = __builtin_amdgcn_exp2f((sS[q][kk] - m) * L2E) * inv;
    }
  }

  int dg = t & 15, ks = t >> 4;
  float acc[8][2] = {};
  int cur = 0;
  for (int kc = 0; kc < K_; kc += 64) {
    if (kc + 64 < K_) {
      const float* kn = keysb + (size_t)(kc + 64) * D_;
#pragma unroll
      for (int e = 0; e < 2; e++) {
        int idx = t * 2 + e;
        int row = idx >> 3, c4 = idx & 7;
        *reinterpret_cast<float4*>(&sK[cur ^ 1][row][c4 * 4]) =
            *reinterpret_cast<const float4*>(&kn[(size_t)row * D_ + c4 * 4]);
      }
    }
#pragma unroll
    for (int i = 0; i < 4; i++) {
      int kk = ks * 4 + i;
      float2 kv = *reinterpret_cast<const float2*>(&sK[cur][kk][dg * 2]);
#pragma unroll
      for (int qq = 0; qq < 8; qq++) {
        float s = sS[qq][kc + kk];
        acc[qq][0] = fmaf(s, kv.x, acc[qq][0]);
        acc[qq][1] = fmaf(s, kv.y, acc[qq][1]);
      }
    }
    __syncthreads();
    cur ^= 1;
  }
  int wave = t >> 6, lane = t & 63;
#pragma unroll
  for (int qq = 0; qq < 8; qq++) {
    acc[qq][0] += __shfl_xor(acc[qq][0], 16, 64);
    acc[qq][1] += __shfl_xor(acc[qq][1], 16, 64);
    acc[qq][0] += __shfl_xor(acc[qq][0], 32, 64);
    acc[qq][1] += __shfl_xor(acc[qq][1], 32, 64);
  }
  if (wave > 0 && lane < 16) {
#pragma unroll
    for (int qq = 0; qq < 8; qq++) {
      sPart[wave - 1][lane][qq * 2] = acc[qq][0];
      sPart[wave - 1][lane][qq * 2 + 1] = acc[qq][1];
    }
  }
  __syncthreads();
  if (wave == 0 && lane < 16) {
#pragma unroll
    for (int qq = 0; qq < 8; qq++) {
      float c0 = acc[qq][0] + sPart[0][lane][qq * 2] +
                 sPart[1][lane][qq * 2] + sPart[2][lane][qq * 2];
      float c1 = acc[qq][1] + sPart[0][lane][qq * 2 + 1] +
                 sPart[1][lane][qq * 2 + 1] + sPart[2][lane][qq * 2 + 1];
      float2 o2 = {c0, c1};
      *reinterpret_cast<float2*>(
          &ctx[((size_t)b * Q_ + q0 + qq) * D_ + d0 + lane * 2]) = o2;
    }
  }
}

// ---------------------------------------------------------------------------
extern "C" void kernel_launch(void* const* d_in, const int* in_sizes, int n_in,
                              void* d_out, int out_size, void* d_ws,
                              size_t ws_size, hipStream_t stream) {
  const float* query = (const float*)d_in[0];
  const float* keys = (const float*)d_in[1];
  const float* Wq = (const float*)d_in[2];
  const float* Wk = (const float*)d_in[3];
  const float* la = (const float*)d_in[4];
  const float* nscalar = (const float*)d_in[5];
  const float* nbias = (const float*)d_in[6];

  float* out = (float*)d_out;
  float* ctx = out;
  float* smx = out + (size_t)B_ * Q_ * D_;

  float* ws = (float*)d_ws;
  float* v = ws + WS_V;
  float* Eq = ws + WS_EQ;
  float* Ek = ws + WS_EK;
  float* S = ws + WS_S;

  if (ws_size >= (size_t)WS_BYTES_MFMA) {
    _Float16* Acvt = (_Float16*)(ws + WS_FLOATS);
    _Float16* Wkcvt = Acvt + AH_ELEMS;
    _Float16* Wqcvt = Wkcvt + WH_ELEMS;
    convert_kernel<<<1409, 256, 0, stream>>>(query, keys, Wq, Wk, la, nscalar,
                                             Acvt, Wkcvt, Wqcvt, v);
    mfma_proj_kernel<<<dim3(72, 8), 256, 0, stream>>>(Acvt, Wkcvt, Wqcvt,
                                                      nbias, Ek, Eq);
  } else {
    compute_v_kernel<<<1, 512, 0, stream>>>(la, nscalar, v);
    proj_gemm_kernel<<<dim3(72, 8), 256, 0, stream>>>(query, keys, Wq, Wk,
                                                      nbias, Eq, Ek);
  }
  scores_kernel<<<dim3(64, 32), 256, 0, stream>>>(Eq, Ek, v, S);
  ctx_kernel<<<dim3(64, 16), 256, 0, stream>>>(S, keys, ctx, smx);
}

// Round 9
// 53.379 us; speedup vs baseline: 1.1055x; 1.0607x over previous
//
#include <hip/hip_runtime.h>

#define B_ 8
#define Q_ 64
#define K_ 512
#define NU_ 512
#define D_ 512

typedef __attribute__((ext_vector_type(8))) _Float16 half8;
typedef __attribute__((ext_vector_type(4))) _Float16 half4;
typedef __attribute__((ext_vector_type(16))) float floatx16;

#define C2F 2.8853900817779268f  // 2*log2(e)

// ws float-layout
#define WS_V 0                   // v[0..511], vtot at [512]
#define WS_EQ 640                // Eq: 8*64*512
#define WS_EK (640 + 262144)     // Ek: 8*512*512
#define WS_S (WS_EK + 2097152)   // S raw scores: 8*64*512
#define WS_FLOATS (WS_S + 262144)
#define AH_ELEMS 2359296         // 8 b * 576 rows (512 keys + 64 query) * 512
#define WH_ELEMS 262144          // 512*512 f16
#define WS_BYTES_MFMA (WS_FLOATS * 4 + (size_t)(AH_ELEMS + 2 * WH_ELEMS) * 2)

#define GLD16(gp, lp)                                                         \
  __builtin_amdgcn_global_load_lds(                                           \
      (const __attribute__((address_space(1))) void*)(gp),                    \
      (__attribute__((address_space(3))) void*)(lp), 16, 0, 0)

// ---------------------------------------------------------------------------
// Kernel 1: f32 -> f16 convert into PRE-SWIZZLED per-batch layout + v.
// Acvt row space: [b][576][512] where rows 0..511 = keys[b], 512..575 =
// query[b]. 16B-block index XOR'd with row&7 within each 128B K-slab so a
// LINEAR global_load_lds copy yields an LDS tile readable with the same XOR.
// XCD pinning: A-blocks decode b = bid&7 -> XCD b converts batch b only.
// Blocks: A 1152 (8b x 144), Wk 128, Wq 128, v 1 -> 1409.
// ---------------------------------------------------------------------------
__global__ __launch_bounds__(256) void convert_kernel(
    const float* __restrict__ query, const float* __restrict__ keys,
    const float* __restrict__ Wq, const float* __restrict__ Wk,
    const float* __restrict__ la, const float* __restrict__ scalar,
    _Float16* __restrict__ Acvt, _Float16* __restrict__ Wkcvt,
    _Float16* __restrict__ Wqcvt, float* __restrict__ v) {
  int bid = blockIdx.x;
  int t = threadIdx.x;
  if (bid == 1408) {  // v block
    __shared__ float red[4], red2[4];
    float x0 = la[t], x1 = la[t + 256];
    float ss = x0 * x0 + x1 * x1;
#pragma unroll
    for (int o = 1; o < 64; o <<= 1) ss += __shfl_xor(ss, o, 64);
    int wave = t >> 6, lane = t & 63;
    if (lane == 0) red[wave] = ss;
    __syncthreads();
    float tot = red[0] + red[1] + red[2] + red[3];
    float sc = rsqrtf(tot) * scalar[0];
    float v0 = x0 * sc, v1 = x1 * sc;
    v[t] = v0;
    v[t + 256] = v1;
    float sv = v0 + v1;
#pragma unroll
    for (int o = 1; o < 64; o <<= 1) sv += __shfl_xor(sv, o, 64);
    if (lane == 0) red2[wave] = sv;
    __syncthreads();
    if (t == 0) v[512] = red2[0] + red2[1] + red2[2] + red2[3];
    return;
  }
  const float* src;
  _Float16* dst;
  int r, bb = t & 63;
  if (bid < 1152) {  // A: XCD-pinned per batch
    int b = bid & 7;
    int i = bid >> 3;            // [0,144) -> 4 rows each
    r = i * 4 + (t >> 6);        // local row in [0,576)
    src = (r < 512) ? keys + ((size_t)b * 512 + r) * 512
                    : query + ((size_t)b * 64 + (r - 512)) * 512;
    dst = Acvt + ((size_t)b * 576 + r) * 512;
  } else if (bid < 1280) {
    int j = bid - 1152;          // [0,128)
    r = j * 4 + (t >> 6);        // [0,512)
    src = Wk + (size_t)r * 512;
    dst = Wkcvt + (size_t)r * 512;
  } else {
    int j = bid - 1280;
    r = j * 4 + (t >> 6);
    src = Wq + (size_t)r * 512;
    dst = Wqcvt + (size_t)r * 512;
  }
  int scol = ((bb & 56) | ((bb ^ r) & 7)) * 8;
  float4 x0 = *reinterpret_cast<const float4*>(src + scol);
  float4 x1 = *reinterpret_cast<const float4*>(src + scol + 4);
  half8 o = {(_Float16)x0.x, (_Float16)x0.y, (_Float16)x0.z, (_Float16)x0.w,
             (_Float16)x1.x, (_Float16)x1.y, (_Float16)x1.z, (_Float16)x1.w};
  *reinterpret_cast<half8*>(dst + bb * 8) = o;
}

// ---------------------------------------------------------------------------
// Kernel 2: MFMA projection, global_load_lds staging, double-buffered LDS,
// XOR-swizzled fragment reads. 64x64 tile, K-step 64, one barrier per step.
// XCD pinning: grid 576 linear, b = bid&7; per b: 9 m-tiles (8 keys + 1
// query) x 8 n-tiles. Epilogue writes Eq = 2^(C2*(pq+bias)), Ek = 2^(C2*pk).
// ---------------------------------------------------------------------------
__global__ __launch_bounds__(256) void mfma_proj_kernel(
    const _Float16* __restrict__ Acvt, const _Float16* __restrict__ Wkcvt,
    const _Float16* __restrict__ Wqcvt, const float* __restrict__ bias,
    float* __restrict__ Ek, float* __restrict__ Eq) {
  __shared__ _Float16 sA[2][64][64];  // 16 KB (linear, pre-swizzled source)
  __shared__ _Float16 sW[2][64][64];  // 16 KB
  int lid = blockIdx.x;       // [0,576)
  int b = lid & 7;
  int rr = lid >> 3;          // [0,72)
  int mtb = rr % 9;           // m-tile within batch: 0..7 keys, 8 query
  int nt = rr / 9;            // [0,8)
  int n0 = nt * 64;
  bool isQ = (mtb == 8);
  const _Float16* Wcvt = isQ ? Wqcvt : Wkcvt;
  size_t mrowbase = (size_t)b * 576 + (size_t)mtb * 64;
  int t = threadIdx.x;
  int wave = t >> 6, lane = t & 63;
  int mw = (wave >> 1) * 32, nw = (wave & 1) * 32;
  int lr = lane & 31, g = lane >> 5;
  int arow = mw + lr, wrow = nw + lr;
  // G2L lane source offsets: region r covers rows r*8..r*8+7
  int lrow = lane >> 3, lblk = lane & 7;  // within a region
  const _Float16* gAbase =
      Acvt + (mrowbase + wave * 16 + lrow) * 512 + lblk * 8;
  const _Float16* gWbase =
      Wcvt + ((size_t)(n0 + wave * 16 + lrow)) * 512 + lblk * 8;

  floatx16 acc;
#pragma unroll
  for (int i = 0; i < 16; i++) acc[i] = 0.f;

  // stage(kt, sel): wave stages regions {2w, 2w+1} (16 rows) of A and W
#define STAGE(kt, sel)                                                        \
  {                                                                           \
    int koff = (kt)*64;                                                       \
    GLD16(gAbase + koff, &sA[sel][wave * 16][0]);                             \
    GLD16(gAbase + koff + 8 * 512, &sA[sel][wave * 16 + 8][0]);               \
    GLD16(gWbase + koff, &sW[sel][wave * 16][0]);                             \
    GLD16(gWbase + koff + 8 * 512, &sW[sel][wave * 16 + 8][0]);               \
  }

  STAGE(0, 0);
  for (int kt = 0; kt < 8; kt++) {
    __syncthreads();  // drains this wave's G2L (compiler full-drain) + sync
    if (kt < 7) STAGE(kt + 1, (kt + 1) & 1);
    int sel = kt & 1;
#pragma unroll
    for (int i = 0; i < 4; i++) {
      int ablk = (((2 * i + g) ^ arow) & 7) * 8 + ((2 * i + g) & ~7) * 8;
      int wblk = (((2 * i + g) ^ wrow) & 7) * 8 + ((2 * i + g) & ~7) * 8;
      half8 af = *reinterpret_cast<const half8*>(&sA[sel][arow][ablk]);
      half8 wf = *reinterpret_cast<const half8*>(&sW[sel][wrow][wblk]);
      acc = __builtin_amdgcn_mfma_f32_32x32x16_f16(af, wf, acc, 0, 0, 0);
    }
  }
#undef STAGE
  int col = n0 + nw + lr;
  float bv = isQ ? bias[col] : 0.f;
#pragma unroll
  for (int r = 0; r < 16; r++) {
    int lrow_out = mtb * 64 + mw + (r & 3) + 8 * (r >> 2) + 4 * g;  // [0,576)
    float e = __builtin_amdgcn_exp2f((acc[r] + bv) * C2F);
    if (isQ)
      Eq[((size_t)b * 64 + (lrow_out - 512)) * NU_ + col] = e;
    else
      Ek[((size_t)b * 512 + lrow_out) * NU_ + col] = e;
  }
}

// ---------------------------------------------------------------------------
// Fallback (ws too small): f32 projection writing Eq/Ek, + v kernel
// ---------------------------------------------------------------------------
__global__ __launch_bounds__(512) void compute_v_kernel(
    const float* __restrict__ la, const float* __restrict__ scalar,
    float* __restrict__ v) {
  __shared__ float red[8], red2[8];
  int t = threadIdx.x;
  float x = la[t];
  float ss = x * x;
#pragma unroll
  for (int o = 1; o < 64; o <<= 1) ss += __shfl_xor(ss, o, 64);
  int wave = t >> 6, lane = t & 63;
  if (lane == 0) red[wave] = ss;
  __syncthreads();
  float tot = 0.f;
#pragma unroll
  for (int w = 0; w < 8; w++) tot += red[w];
  float vv = x * rsqrtf(tot) * scalar[0];
  v[t] = vv;
  float sv = vv;
#pragma unroll
  for (int o = 1; o < 64; o <<= 1) sv += __shfl_xor(sv, o, 64);
  if (lane == 0) red2[wave] = sv;
  __syncthreads();
  if (t == 0) {
    float s = 0.f;
#pragma unroll
    for (int w = 0; w < 8; w++) s += red2[w];
    v[512] = s;
  }
}

__global__ __launch_bounds__(256) void proj_gemm_kernel(
    const float* __restrict__ query, const float* __restrict__ keys,
    const float* __restrict__ Wq, const float* __restrict__ Wk,
    const float* __restrict__ bias, float* __restrict__ Eq,
    float* __restrict__ Ek) {
  __shared__ __align__(16) float As[16][68];
  __shared__ __align__(16) float Bs[16][68];
  int mt = blockIdx.x;
  int n0 = blockIdx.y * 64;
  const float* A;
  const float* W;
  float* C;
  bool ub;
  if (mt < 8) {
    A = query + (size_t)mt * 64 * D_;
    W = Wq;
    C = Eq + (size_t)mt * 64 * NU_;
    ub = true;
  } else {
    A = keys + (size_t)(mt - 8) * 64 * D_;
    W = Wk;
    C = Ek + (size_t)(mt - 8) * 64 * NU_;
    ub = false;
  }
  int t = threadIdx.x;
  int tx = t & 15, ty = t >> 4;
  int ld = t & 15, lm = t >> 4;
  float acc[4][4] = {};
  for (int d0 = 0; d0 < D_; d0 += 16) {
#pragma unroll
    for (int r = 0; r < 4; r++) {
      As[ld][lm + 16 * r] = A[(size_t)(lm + 16 * r) * D_ + d0 + ld];
      Bs[ld][lm + 16 * r] = W[(size_t)(n0 + lm + 16 * r) * D_ + d0 + ld];
    }
    __syncthreads();
#pragma unroll
    for (int dd = 0; dd < 16; dd++) {
      float4 a4 = *reinterpret_cast<const float4*>(&As[dd][ty * 4]);
      float4 b4 = *reinterpret_cast<const float4*>(&Bs[dd][tx * 4]);
      float av[4] = {a4.x, a4.y, a4.z, a4.w};
      float bv[4] = {b4.x, b4.y, b4.z, b4.w};
#pragma unroll
      for (int i = 0; i < 4; i++)
#pragma unroll
        for (int j = 0; j < 4; j++)
          acc[i][j] = fmaf(av[i], bv[j], acc[i][j]);
    }
    __syncthreads();
  }
#pragma unroll
  for (int i = 0; i < 4; i++) {
    float4 o;
    float* op = &o.x;
#pragma unroll
    for (int j = 0; j < 4; j++) {
      float val = acc[i][j];
      if (ub) val += bias[n0 + tx * 4 + j];
      op[j] = __builtin_amdgcn_exp2f(val * C2F);
    }
    *reinterpret_cast<float4*>(&C[(size_t)(ty * 4 + i) * NU_ + n0 + tx * 4]) = o;
  }
}

// ---------------------------------------------------------------------------
// Kernel 3: scores. Grid 2048 linear, XCD-pinned: b = bid&7, qt, kt.
// 4 waves: uw = wave>>1 (u half), kw = wave&1 (k half of 16).
// Pairwise rational combine: 1 rcp per 2 u-terms.
// S[q,k] = vtot - 2 * sum_u v[u] / (1 + Eq[q,u]*Ek[k,u])
// ---------------------------------------------------------------------------
__global__ __launch_bounds__(256) void scores_kernel(
    const float* __restrict__ Eq, const float* __restrict__ Ek,
    const float* __restrict__ v, float* __restrict__ S) {
  __shared__ __align__(16) float sEq[8][NU_];  // 16 KB
  __shared__ __align__(16) float sV[NU_];      // 2 KB
  __shared__ float sRed[2][8][8];              // 512 B
  int lid = blockIdx.x;
  int b = lid & 7;
  int rrr = lid >> 3;          // [0,256)
  int qt = rrr & 7, kt = rrr >> 3;  // kt [0,32)
  int q0 = qt * 8, k0 = kt * 16;
  int t = threadIdx.x;
  const float4* eqsrc =
      reinterpret_cast<const float4*>(Eq + ((size_t)b * Q_ + q0) * NU_);
#pragma unroll
  for (int i = 0; i < 4; i++)
    reinterpret_cast<float4*>(&sEq[0][0])[t + 256 * i] = eqsrc[t + 256 * i];
  if (t < 128)
    reinterpret_cast<float4*>(sV)[t] = reinterpret_cast<const float4*>(v)[t];
  float vtot = v[512];
  __syncthreads();

  int wave = t >> 6, lane = t & 63;
  int uw = wave >> 1, kw = wave & 1;
  int klane = lane >> 3, ulane = lane & 7;
  int k = k0 + kw * 8 + klane;
  const float* ekr = Ek + ((size_t)b * K_ + k) * NU_;
  float acc[8] = {};
#pragma unroll 2
  for (int j = 0; j < 8; j++) {
    int u = uw * 256 + ulane * 4 + 32 * j;
    float4 ek4 = *reinterpret_cast<const float4*>(ekr + u);
    float4 v4 = *reinterpret_cast<const float4*>(&sV[u]);
#pragma unroll
    for (int qq = 0; qq < 8; qq++) {
      float4 eq4 = *reinterpret_cast<const float4*>(&sEq[qq][u]);
      float p0 = fmaf(eq4.x, ek4.x, 1.f);
      float p1 = fmaf(eq4.y, ek4.y, 1.f);
      float p2 = fmaf(eq4.z, ek4.z, 1.f);
      float p3 = fmaf(eq4.w, ek4.w, 1.f);
      float n01 = fmaf(v4.x, p1, v4.y * p0);
      float n23 = fmaf(v4.z, p3, v4.w * p2);
      float r01 = __builtin_amdgcn_rcpf(p0 * p1);
      float r23 = __builtin_amdgcn_rcpf(p2 * p3);
      acc[qq] = fmaf(n01, r01, acc[qq]);
      acc[qq] = fmaf(n23, r23, acc[qq]);
    }
  }
#pragma unroll
  for (int qq = 0; qq < 8; qq++) {
    acc[qq] += __shfl_xor(acc[qq], 1, 64);
    acc[qq] += __shfl_xor(acc[qq], 2, 64);
    acc[qq] += __shfl_xor(acc[qq], 4, 64);
  }
  if (uw == 1 && ulane == 0) {
#pragma unroll
    for (int qq = 0; qq < 8; qq++) sRed[kw][klane][qq] = acc[qq];
  }
  __syncthreads();
  if (uw == 0 && ulane == 0) {
#pragma unroll
    for (int qq = 0; qq < 8; qq++) {
      float a = acc[qq] + sRed[kw][klane][qq];
      S[((size_t)b * Q_ + q0 + qq) * K_ + k] = fmaf(-2.f, a, vtot);
    }
  }
}

// ---------------------------------------------------------------------------
// Kernel 4: softmax (dt==0 writes smx) + context. Grid 1024 linear,
// XCD-pinned: b = bid&7, qt, dt (dtile 32).
// ---------------------------------------------------------------------------
__global__ __launch_bounds__(256) void ctx_kernel(
    const float* __restrict__ S, const float* __restrict__ keys,
    float* __restrict__ ctx, float* __restrict__ smx) {
  __shared__ __align__(16) float sS[8][K_];      // 16 KB
  __shared__ __align__(16) float sK[2][64][32];  // 16 KB
  __shared__ float sPart[3][16][16];             // 3 KB
  int lid = blockIdx.x;
  int b = lid & 7;
  int rrr = lid >> 3;          // [0,128)
  int qt = rrr & 7, dt = rrr >> 3;  // dt [0,16)
  int q0 = qt * 8, d0 = dt * 32;
  int t = threadIdx.x;
  const float4* ssrc =
      reinterpret_cast<const float4*>(S + ((size_t)b * Q_ + q0) * K_);
#pragma unroll
  for (int i = 0; i < 4; i++)
    reinterpret_cast<float4*>(&sS[0][0])[t + 256 * i] = ssrc[t + 256 * i];
  const float* keysb = keys + (size_t)b * K_ * D_ + d0;
#pragma unroll
  for (int e = 0; e < 2; e++) {
    int idx = t * 2 + e;
    int row = idx >> 3, c4 = idx & 7;
    *reinterpret_cast<float4*>(&sK[0][row][c4 * 4]) =
        *reinterpret_cast<const float4*>(&keysb[(size_t)row * D_ + c4 * 4]);
  }
  __syncthreads();

  {
    int q = t >> 5, lg = t & 31;
    float m = -1e30f;
    for (int kk = lg; kk < K_; kk += 32) m = fmaxf(m, sS[q][kk]);
#pragma unroll
    for (int o = 1; o < 32; o <<= 1) m = fmaxf(m, __shfl_xor(m, o, 64));
    const float L2E = 1.4426950408889634f;
    float sum = 0.f;
    for (int kk = lg; kk < K_; kk += 32)
      sum += __builtin_amdgcn_exp2f((sS[q][kk] - m) * L2E);
#pragma unroll
    for (int o = 1; o < 32; o <<= 1) sum += __shfl_xor(sum, o, 64);
    if (dt == 0) {
      float inv = 1.f / sum;
      float* dst = smx + ((size_t)b * Q_ + q0 + q) * K_;
      for (int kk = lg; kk < K_; kk += 32)
        dst[kk] = __builtin_amdgcn_exp2f((sS[q][kk] - m) * L2E) * inv;
    }
  }

  int dg = t & 15, ks = t >> 4;
  float acc[8][2] = {};
  int cur = 0;
  for (int kc = 0; kc < K_; kc += 64) {
    if (kc + 64 < K_) {
      const float* kn = keysb + (size_t)(kc + 64) * D_;
#pragma unroll
      for (int e = 0; e < 2; e++) {
        int idx = t * 2 + e;
        int row = idx >> 3, c4 = idx & 7;
        *reinterpret_cast<float4*>(&sK[cur ^ 1][row][c4 * 4]) =
            *reinterpret_cast<const float4*>(&kn[(size_t)row * D_ + c4 * 4]);
      }
    }
#pragma unroll
    for (int i = 0; i < 4; i++) {
      int kk = ks * 4 + i;
      float2 kv = *reinterpret_cast<const float2*>(&sK[cur][kk][dg * 2]);
#pragma unroll
      for (int qq = 0; qq < 8; qq++) {
        float s = sS[qq][kc + kk];
        acc[qq][0] = fmaf(s, kv.x, acc[qq][0]);
        acc[qq][1] = fmaf(s, kv.y, acc[qq][1]);
      }
    }
    __syncthreads();
    cur ^= 1;
  }
  int wave = t >> 6, lane = t & 63;
#pragma unroll
  for (int qq = 0; qq < 8; qq++) {
    acc[qq][0] += __shfl_xor(acc[qq][0], 16, 64);
    acc[qq][1] += __shfl_xor(acc[qq][1], 16, 64);
    acc[qq][0] += __shfl_xor(acc[qq][0], 32, 64);
    acc[qq][1] += __shfl_xor(acc[qq][1], 32, 64);
  }
  if (wave > 0 && lane < 16) {
#pragma unroll
    for (int qq = 0; qq < 8; qq++) {
      sPart[wave - 1][lane][qq * 2] = acc[qq][0];
      sPart[wave - 1][lane][qq * 2 + 1] = acc[qq][1];
    }
  }
  __syncthreads();
  if (wave == 0 && lane < 16) {
#pragma unroll
    for (int qq = 0; qq < 8; qq++) {
      float c0 = acc[qq][0] + sPart[0][lane][qq * 2] +
                 sPart[1][lane][qq * 2] + sPart[2][lane][qq * 2];
      float c1 = acc[qq][1] + sPart[0][lane][qq * 2 + 1] +
                 sPart[1][lane][qq * 2 + 1] + sPart[2][lane][qq * 2 + 1];
      float2 o2 = {c0, c1};
      *reinterpret_cast<float2*>(
          &ctx[((size_t)b * Q_ + q0 + qq) * D_ + d0 + lane * 2]) = o2;
    }
  }
}

// ---------------------------------------------------------------------------
extern "C" void kernel_launch(void* const* d_in, const int* in_sizes, int n_in,
                              void* d_out, int out_size, void* d_ws,
                              size_t ws_size, hipStream_t stream) {
  const float* query = (const float*)d_in[0];
  const float* keys = (const float*)d_in[1];
  const float* Wq = (const float*)d_in[2];
  const float* Wk = (const float*)d_in[3];
  const float* la = (const float*)d_in[4];
  const float* nscalar = (const float*)d_in[5];
  const float* nbias = (const float*)d_in[6];

  float* out = (float*)d_out;
  float* ctx = out;
  float* smx = out + (size_t)B_ * Q_ * D_;

  float* ws = (float*)d_ws;
  float* v = ws + WS_V;
  float* Eq = ws + WS_EQ;
  float* Ek = ws + WS_EK;
  float* S = ws + WS_S;

  if (ws_size >= (size_t)WS_BYTES_MFMA) {
    _Float16* Acvt = (_Float16*)(ws + WS_FLOATS);
    _Float16* Wkcvt = Acvt + AH_ELEMS;
    _Float16* Wqcvt = Wkcvt + WH_ELEMS;
    convert_kernel<<<1409, 256, 0, stream>>>(query, keys, Wq, Wk, la, nscalar,
                                             Acvt, Wkcvt, Wqcvt, v);
    mfma_proj_kernel<<<576, 256, 0, stream>>>(Acvt, Wkcvt, Wqcvt, nbias, Ek,
                                              Eq);
  } else {
    compute_v_kernel<<<1, 512, 0, stream>>>(la, nscalar, v);
    proj_gemm_kernel<<<dim3(72, 8), 256, 0, stream>>>(query, keys, Wq, Wk,
                                                      nbias, Eq, Ek);
  }
  scores_kernel<<<2048, 256, 0, stream>>>(Eq, Ek, v, S);
  ctx_kernel<<<1024, 256, 0, stream>>>(S, keys, ctx, smx);
}